// Round 27
// baseline (171.003 us; speedup 1.0000x reference)
//
#include <hip/hip_runtime.h>
#include <hip/hip_bf16.h>
#include <math.h>

#define BB 8
#define NN 200000
#define CC 81
#define TOPK 200
#define CAP 16384             // per-batch candidate capacity (true c ~5-8K)
#define SVCAP 2048            // survivor capacity (typ. ~210)
#define NBIN 4096
#define THKEY 0x3E800000u     // bits of 0.25f (prefilter threshold)
#define MAGIC 0x5A17C0DEu     // protocol tag: cnt line initialized by final

static __device__ __forceinline__ int bin_of(unsigned key) {
    return (int)((key >> 14) & (NBIN - 1));
}

// ---------------------------------------------------------------------------
// Kernel A (unchanged from R26, passed): scores pipeline + two-phase append.
// ---------------------------------------------------------------------------
__global__ __launch_bounds__(256) void scores_kernel(const float* __restrict__ logits,
                                                     float* __restrict__ scores,
                                                     unsigned long long* __restrict__ cand,
                                                     int* __restrict__ cnt) {
    __shared__ float ls[64 * CC];     // 5184 floats = 20.7 KB
    __shared__ float lsc[64];
    __shared__ unsigned long long lbuf[64];
    __shared__ int s_app, s_base;
    int tid = threadIdx.x;
    int b = blockIdx.y;
    if (tid == 0) s_app = 0;
    size_t fbase = ((size_t)b * NN + (size_t)blockIdx.x * 64) * CC;  // 16B-aligned
    const float4* g4 = (const float4*)(logits + fbase);
    float4* l4 = (float4*)ls;

    int wbase = tid & ~63;            // wave-uniform base within block
#pragma unroll
    for (int k = 0; k < 5; ++k) {     // 5 full wave rounds = 1280 float4s
        __builtin_amdgcn_global_load_lds(
            (const __attribute__((address_space(1))) void*)(g4 + k * 256 + tid),
            (__attribute__((address_space(3))) void*)(l4 + k * 256 + wbase),
            16, 0, 0);
    }
    if (tid < 16) l4[1280 + tid] = g4[1280 + tid];   // tail 16 f4s, plain copy
    __syncthreads();                  // drains vmcnt incl. global_load_lds

    int r = tid >> 2;                 // row 0..63
    int q = tid & 3;                  // quarter
    const float* row = ls + r * CC;
    int head = (4 - (r & 3)) & 3;     // floats until 16B alignment (81r%4==r%4)
    int nf4 = (CC - head) >> 2;       // 19 or 20 aligned float4s
    int tail = CC - head - 4 * nf4;   // 0..3

    float m = -INFINITY, S = 0.0f;
    const float4* rp = (const float4*)(row + head);
    for (int j = q; j < nf4; j += 4) {
        float4 v = rp[j];
        m = fmaxf(fmaxf(fmaxf(m, v.x), v.y), fmaxf(v.z, v.w));
        S += __expf(v.x) + __expf(v.y) + __expf(v.z) + __expf(v.w);
    }
    if (q == 3) {
        for (int h2 = 0; h2 < head; ++h2) { float x = row[h2]; m = fmaxf(m, x); S += __expf(x); }
        for (int t2 = 0; t2 < tail; ++t2) { float x = row[CC - tail + t2]; m = fmaxf(m, x); S += __expf(x); }
    }
#pragma unroll
    for (int w = 1; w < 4; w <<= 1) {
        m = fmaxf(m, __shfl_xor(m, w, 64));
        S += __shfl_xor(S, w, 64);
    }
    if (q == 0) {
        float s = __expf(m) / S;
        lsc[r] = s;
        unsigned key = __float_as_uint(s);
        if (key >= THKEY) {
            int p = atomicAdd(&s_app, 1);        // LDS atomic, <=64 per block
            lbuf[p] = ((unsigned long long)key << 32) |
                      (unsigned)(blockIdx.x * 64 + r);
        }
    }
    __syncthreads();
    if (tid < 64) scores[(size_t)b * NN + (size_t)blockIdx.x * 64 + tid] = lsc[tid];
    int na = s_app;
    if (na > 0) {
        if (tid == 0) s_base = atomicAdd(&cnt[b * 32], na);   // ONE global RMW
        __syncthreads();
        if (tid < na) {
            int pos = s_base + tid;
            if (pos >= 0 && pos < CAP) cand[(size_t)b * CAP + pos] = lbuf[tid];
        }
    }
}

// ---------------------------------------------------------------------------
// rank_bin (unchanged, proven).
// ---------------------------------------------------------------------------
static __device__ __forceinline__ int rank_bin(unsigned* h, unsigned* wtot,
                                               int* s_t, int tid) {
    int lane = tid & 63, wv = tid >> 6;
    unsigned s = 0;
    int hi = NBIN - 1 - 16 * tid;
    if (tid < 256) {
#pragma unroll
        for (int j = 0; j < 16; ++j) s += h[hi - j];
    }
    unsigned inc = s;
#pragma unroll
    for (int d = 1; d < 64; d <<= 1) {
        unsigned o = __shfl_up(inc, d, 64);
        if (lane >= d) inc += o;
    }
    if (tid < 256 && lane == 63) wtot[wv] = inc;
    __syncthreads();
    if (tid < 256) {
        unsigned before = inc - s;
        for (int wp = 0; wp < wv; ++wp) before += wtot[wp];
        if (before < TOPK && before + s >= TOPK) {
            unsigned cum = before;
            for (int j = 0; j < 16; ++j) {
                cum += h[hi - j];
                if (cum >= TOPK) { *s_t = hi - j; break; }
            }
        }
    }
    __syncthreads();
    return *s_t;
}

// ---------------------------------------------------------------------------
// Kernel F (R26's v9 + do_reset flag). MEASUREMENT: launched TWICE; first
// with do_reset=0 (leaves cnt intact -> second sees identical state), second
// with do_reset=1 (normal protocol). dur_us - 140.7 == one final launch+run.
// ---------------------------------------------------------------------------
__global__ __launch_bounds__(1024) void final_kernel(const float* __restrict__ scores,
                                                     const float* __restrict__ segs,
                                                     unsigned long long* __restrict__ cand,
                                                     int* __restrict__ cnt,
                                                     int* __restrict__ out,
                                                     int do_reset) {
    __shared__ unsigned h[NBIN];                                 // 16 KB
    __shared__ unsigned wtot[4];
    __shared__ int s_t, s_cnt;
    __shared__ __align__(16) unsigned long long sv[SVCAP + 2];   // 16.4 KB
    __shared__ __align__(16) unsigned long long sel[TOPK];
    __shared__ __align__(16) unsigned long long pk2[TOPK];
    __shared__ int nms_i[256];
    __shared__ float2 nms_xy[256];
    __shared__ __align__(32) unsigned long long krow[TOPK][4];   // 6.4 KB

    int b = blockIdx.x;
    int tid = threadIdx.x;
    const float* sc = scores + (size_t)b * NN;
    const float* sg = segs + (size_t)b * NN * 2;
    unsigned long long* cb = cand + (size_t)b * CAP;

    for (int i = tid; i < TOPK; i += 1024) {
        out[b * TOPK + i] = 0;
        out[(BB + b) * TOPK + i] = 0;
    }
    if (tid < 256) { nms_xy[tid] = make_float2(0.f, 0.f); nms_i[tid] = 0; }
    for (int i = tid; i < NBIN; i += 1024) h[i] = 0u;
    if (tid == 0) s_cnt = 0;

    int c = cnt[b * 32];
    unsigned mg = (unsigned)cnt[b * 32 + 1];
    __syncthreads();                  // all threads have read c/mg
    if (do_reset && tid == 0) { cnt[b * 32] = 0; cnt[b * 32 + 1] = (int)MAGIC; }

    int M;
    if (mg == MAGIC && c >= TOPK && c <= CAP) {
        M = c;                         // FAST: candidates valid in cand
    } else {
        // SLOW: full-scan hist -> threshold -> gather into cand
        const float4* sc4 = (const float4*)sc;
        for (int i = tid; i < NN / 4; i += 1024) {
            float4 v = sc4[i];
            atomicAdd(&h[bin_of(__float_as_uint(v.x))], 1u);
            atomicAdd(&h[bin_of(__float_as_uint(v.y))], 1u);
            atomicAdd(&h[bin_of(__float_as_uint(v.z))], 1u);
            atomicAdd(&h[bin_of(__float_as_uint(v.w))], 1u);
        }
        __syncthreads();
        int t = rank_bin(h, wtot, &s_t, tid);
        for (int i = tid; i < NN / 4; i += 1024) {
            float4 v = sc4[i];
            unsigned keys[4] = { __float_as_uint(v.x), __float_as_uint(v.y),
                                 __float_as_uint(v.z), __float_as_uint(v.w) };
#pragma unroll
            for (int j = 0; j < 4; ++j) {
                if (bin_of(keys[j]) >= t) {
                    int pos = atomicAdd(&s_cnt, 1);   // LDS atomic
                    if (pos < CAP)
                        cb[pos] = ((unsigned long long)keys[j] << 32) |
                                  (unsigned)(4 * i + j);
                }
            }
        }
        __syncthreads();
        M = s_cnt; if (M > CAP) M = CAP;
        for (int i = tid; i < NBIN; i += 1024) h[i] = 0u;
        if (tid == 0) s_cnt = 0;
        __syncthreads();
    }

    // ---- candidate hist (stream from global, L2-hot) ----
    for (int j = tid; j < M; j += 1024)
        atomicAdd(&h[bin_of((unsigned)(cb[j] >> 32))], 1u);
    __syncthreads();
    int t2 = rank_bin(h, wtot, &s_t, tid);

    // ---- survivors (bin >= t2) -> LDS; ~210 expected ----
    for (int j = tid; j < M; j += 1024) {
        unsigned long long p = cb[j];
        if (bin_of((unsigned)(p >> 32)) >= t2) {
            int q = atomicAdd(&s_cnt, 1);
            if (q < SVCAP) sv[q] = p;
        }
    }
    __syncthreads();
    int M2 = s_cnt; if (M2 > SVCAP) M2 = SVCAP;
    if (tid == 0) { sv[M2] = 0ull; sv[M2 + 1] = 0ull; }   // pad for b128 reads
    __syncthreads();

    // ---- exact rank by (key desc, idx desc): packed u64, b128 reads ----
    {
        int Mh = (M2 + 1) >> 1;
        const ulonglong2* v2 = (const ulonglong2*)sv;
        for (int j = tid; j < M2; j += 1024) {
            unsigned long long pj = sv[j];
            int rank = 0;
#pragma unroll 4
            for (int mm = 0; mm < Mh; ++mm) {
                ulonglong2 v = v2[mm];
                rank += (v.x > pj) + (v.y > pj);      // 0-pad never counts
            }
            if (rank < TOPK) sel[rank] = pj;
        }
    }
    __syncthreads();

    // ---- NMS-order re-rank: (key<<32)|~idx == (key desc, idx asc) ----
    if (tid < TOPK) {
        unsigned long long p = sel[tid];
        pk2[tid] = (p & 0xffffffff00000000ull) | (unsigned)(~(unsigned)p);
    }
    __syncthreads();
    if (tid < TOPK) {
        unsigned long long pj = pk2[tid];
        int r2 = 0;
        const ulonglong2* p2 = (const ulonglong2*)pk2;
#pragma unroll 4
        for (int mm = 0; mm < TOPK / 2; ++mm) {
            ulonglong2 v = p2[mm];
            r2 += (v.x > pj) + (v.y > pj);
        }
        int idx = (int)(~(unsigned)pj);
        nms_i[r2] = idx;
        nms_xy[r2] = make_float2(sg[2 * (size_t)idx], sg[2 * (size_t)idx + 1]);
    }
    __syncthreads();

    // ---- kill matrix (parallel ballots) ----
    {
        int lane = tid & 63, wv = tid >> 6;
        for (int p = wv; p < TOPK; p += 16) {
            float2 w = nms_xy[p];
#pragma unroll
            for (int k = 0; k < 4; ++k) {
                int j = k * 64 + lane;
                float2 bj = nms_xy[j];
                bool kill = false;
                if (j < TOPK) {
                    if (j == p) kill = true;
                    else {
                        float inter = fminf(bj.y, w.y) - fmaxf(bj.x, w.x);
                        kill = inter > 0.f;
                    }
                }
                unsigned long long bm = __ballot(kill);
                if (lane == 0) krow[p][k] = bm;
            }
        }
    }
    __syncthreads();

    // ---- single-thread greedy scan (proven) ----
    if (tid == 0) {
        unsigned long long m0 = ~0ull, m1 = ~0ull, m2 = ~0ull, m3 = 0xffull;
        int* keep = out + b * TOPK;
        for (int it = 0; it < TOPK; ++it) {
            int p;
            if (m0)      p = __ffsll(m0) - 1;
            else if (m1) p = 64 + __ffsll(m1) - 1;
            else if (m2) p = 128 + __ffsll(m2) - 1;
            else if (m3) p = 192 + __ffsll(m3) - 1;
            else break;
            keep[it] = nms_i[p];
            m0 &= ~krow[p][0];
            m1 &= ~krow[p][1];
            m2 &= ~krow[p][2];
            m3 &= ~krow[p][3];
        }
    }
}

extern "C" void kernel_launch(void* const* d_in, const int* in_sizes, int n_in,
                              void* d_out, int out_size, void* d_ws, size_t ws_size,
                              hipStream_t stream) {
    const float* logits = (const float*)d_in[0];   // (8, 200000, 81) f32
    const float* segs   = (const float*)d_in[1];   // (8, 200000, 2)  f32
    int* out = (int*)d_out;                        // (16, 200) int32

    char* ws = (char*)d_ws;
    float*              scores = (float*)ws;                            // 6,400,000 B
    unsigned long long* cand   = (unsigned long long*)(ws + 6400000);   // 8*16384*8 = 1,048,576 B
    int*                cnt    = (int*)(ws + 6400000 + 1048576);        // 8 lines (1 KB)

    dim3 sgrid(NN / 64, BB);                       // 3125 x 8
    scores_kernel<<<sgrid, 256, 0, stream>>>(logits, scores, cand, cnt);
    // MEASUREMENT: final twice. First leaves cnt intact (do_reset=0), second
    // consumes it (do_reset=1). dur_us - 140.7 == one final launch+run.
    final_kernel<<<BB, 1024, 0, stream>>>(scores, segs, cand, cnt, out, 0);
    final_kernel<<<BB, 1024, 0, stream>>>(scores, segs, cand, cnt, out, 1);
}

// Round 28
// 149.679 us; speedup vs baseline: 1.1425x; 1.1425x over previous
//
#include <hip/hip_runtime.h>
#include <hip/hip_bf16.h>
#include <math.h>

#define BB 8
#define NN 200000
#define CC 81
#define TOPK 200
#define CAP 16384             // per-batch candidate capacity (true c ~5-8K)
#define SVCAP 2048            // survivor capacity (typ. ~210)
#define NBIN 4096
#define THKEY 0x3E800000u     // bits of 0.25f (prefilter threshold)
#define MAGIC 0x5A17C0DEu     // protocol tag: cnt line initialized by final

static __device__ __forceinline__ int bin_of(unsigned key) {
    return (int)((key >> 14) & (NBIN - 1));
}

// ---------------------------------------------------------------------------
// Kernel A (unchanged, passed R26/R27): scores pipeline + two-phase append.
// ---------------------------------------------------------------------------
__global__ __launch_bounds__(256) void scores_kernel(const float* __restrict__ logits,
                                                     float* __restrict__ scores,
                                                     unsigned long long* __restrict__ cand,
                                                     int* __restrict__ cnt) {
    __shared__ float ls[64 * CC];     // 5184 floats = 20.7 KB
    __shared__ float lsc[64];
    __shared__ unsigned long long lbuf[64];
    __shared__ int s_app, s_base;
    int tid = threadIdx.x;
    int b = blockIdx.y;
    if (tid == 0) s_app = 0;
    size_t fbase = ((size_t)b * NN + (size_t)blockIdx.x * 64) * CC;  // 16B-aligned
    const float4* g4 = (const float4*)(logits + fbase);
    float4* l4 = (float4*)ls;

    int wbase = tid & ~63;            // wave-uniform base within block
#pragma unroll
    for (int k = 0; k < 5; ++k) {     // 5 full wave rounds = 1280 float4s
        __builtin_amdgcn_global_load_lds(
            (const __attribute__((address_space(1))) void*)(g4 + k * 256 + tid),
            (__attribute__((address_space(3))) void*)(l4 + k * 256 + wbase),
            16, 0, 0);
    }
    if (tid < 16) l4[1280 + tid] = g4[1280 + tid];   // tail 16 f4s, plain copy
    __syncthreads();                  // drains vmcnt incl. global_load_lds

    int r = tid >> 2;                 // row 0..63
    int q = tid & 3;                  // quarter
    const float* row = ls + r * CC;
    int head = (4 - (r & 3)) & 3;     // floats until 16B alignment (81r%4==r%4)
    int nf4 = (CC - head) >> 2;       // 19 or 20 aligned float4s
    int tail = CC - head - 4 * nf4;   // 0..3

    float m = -INFINITY, S = 0.0f;
    const float4* rp = (const float4*)(row + head);
    for (int j = q; j < nf4; j += 4) {
        float4 v = rp[j];
        m = fmaxf(fmaxf(fmaxf(m, v.x), v.y), fmaxf(v.z, v.w));
        S += __expf(v.x) + __expf(v.y) + __expf(v.z) + __expf(v.w);
    }
    if (q == 3) {
        for (int h2 = 0; h2 < head; ++h2) { float x = row[h2]; m = fmaxf(m, x); S += __expf(x); }
        for (int t2 = 0; t2 < tail; ++t2) { float x = row[CC - tail + t2]; m = fmaxf(m, x); S += __expf(x); }
    }
#pragma unroll
    for (int w = 1; w < 4; w <<= 1) {
        m = fmaxf(m, __shfl_xor(m, w, 64));
        S += __shfl_xor(S, w, 64);
    }
    if (q == 0) {
        float s = __expf(m) / S;
        lsc[r] = s;
        unsigned key = __float_as_uint(s);
        if (key >= THKEY) {
            int p = atomicAdd(&s_app, 1);        // LDS atomic, <=64 per block
            lbuf[p] = ((unsigned long long)key << 32) |
                      (unsigned)(blockIdx.x * 64 + r);
        }
    }
    __syncthreads();
    if (tid < 64) scores[(size_t)b * NN + (size_t)blockIdx.x * 64 + tid] = lsc[tid];
    int na = s_app;
    if (na > 0) {
        if (tid == 0) s_base = atomicAdd(&cnt[b * 32], na);   // ONE global RMW
        __syncthreads();
        if (tid < na) {
            int pos = s_base + tid;
            if (pos >= 0 && pos < CAP) cand[(size_t)b * CAP + pos] = lbuf[tid];
        }
    }
}

// ---------------------------------------------------------------------------
// rank_bin (unchanged, proven).
// ---------------------------------------------------------------------------
static __device__ __forceinline__ int rank_bin(unsigned* h, unsigned* wtot,
                                               int* s_t, int tid) {
    int lane = tid & 63, wv = tid >> 6;
    unsigned s = 0;
    int hi = NBIN - 1 - 16 * tid;
    if (tid < 256) {
#pragma unroll
        for (int j = 0; j < 16; ++j) s += h[hi - j];
    }
    unsigned inc = s;
#pragma unroll
    for (int d = 1; d < 64; d <<= 1) {
        unsigned o = __shfl_up(inc, d, 64);
        if (lane >= d) inc += o;
    }
    if (tid < 256 && lane == 63) wtot[wv] = inc;
    __syncthreads();
    if (tid < 256) {
        unsigned before = inc - s;
        for (int wp = 0; wp < wv; ++wp) before += wtot[wp];
        if (before < TOPK && before + s >= TOPK) {
            unsigned cum = before;
            for (int j = 0; j < 16; ++j) {
                cum += h[hi - j];
                if (cum >= TOPK) { *s_t = hi - j; break; }
            }
        }
    }
    __syncthreads();
    return *s_t;
}

// ---------------------------------------------------------------------------
// Kernel F (v10 = R26's v9 + trivial-mask greedy scan): measured 30.3us
// (R27); largest phase was the ~115-iteration x ~150cy LDS-chain greedy
// scan. ~100 kept winners are "trivial" (kill row == {self}; degenerate
// boxes x2<x1 can neither suppress nor be suppressed). New: 256-bit triv
// mask built by parallel ballots; thread-0 scan handles trivial winners
// with a register bit-clear (no LDS read); only ~15 non-trivial winners
// pay the LDS round-trip. Decisions bit-identical.
// ---------------------------------------------------------------------------
__global__ __launch_bounds__(1024) void final_kernel(const float* __restrict__ scores,
                                                     const float* __restrict__ segs,
                                                     unsigned long long* __restrict__ cand,
                                                     int* __restrict__ cnt,
                                                     int* __restrict__ out) {
    __shared__ unsigned h[NBIN];                                 // 16 KB
    __shared__ unsigned wtot[4];
    __shared__ int s_t, s_cnt;
    __shared__ __align__(16) unsigned long long sv[SVCAP + 2];   // 16.4 KB
    __shared__ __align__(16) unsigned long long sel[TOPK];
    __shared__ __align__(16) unsigned long long pk2[TOPK];
    __shared__ int nms_i[256];
    __shared__ float2 nms_xy[256];
    __shared__ __align__(32) unsigned long long krow[TOPK][4];   // 6.4 KB
    __shared__ unsigned long long trivm[4];

    int b = blockIdx.x;
    int tid = threadIdx.x;
    const float* sc = scores + (size_t)b * NN;
    const float* sg = segs + (size_t)b * NN * 2;
    unsigned long long* cb = cand + (size_t)b * CAP;

    for (int i = tid; i < TOPK; i += 1024) {
        out[b * TOPK + i] = 0;
        out[(BB + b) * TOPK + i] = 0;
    }
    if (tid < 256) { nms_xy[tid] = make_float2(0.f, 0.f); nms_i[tid] = 0; }
    for (int i = tid; i < NBIN; i += 1024) h[i] = 0u;
    if (tid == 0) s_cnt = 0;

    int c = cnt[b * 32];
    unsigned mg = (unsigned)cnt[b * 32 + 1];
    __syncthreads();                  // all threads have read c/mg
    if (tid == 0) { cnt[b * 32] = 0; cnt[b * 32 + 1] = (int)MAGIC; }  // next replay

    int M;
    if (mg == MAGIC && c >= TOPK && c <= CAP) {
        M = c;                         // FAST: candidates valid in cand
    } else {
        // SLOW: full-scan hist -> threshold -> gather into cand
        const float4* sc4 = (const float4*)sc;
        for (int i = tid; i < NN / 4; i += 1024) {
            float4 v = sc4[i];
            atomicAdd(&h[bin_of(__float_as_uint(v.x))], 1u);
            atomicAdd(&h[bin_of(__float_as_uint(v.y))], 1u);
            atomicAdd(&h[bin_of(__float_as_uint(v.z))], 1u);
            atomicAdd(&h[bin_of(__float_as_uint(v.w))], 1u);
        }
        __syncthreads();
        int t = rank_bin(h, wtot, &s_t, tid);
        for (int i = tid; i < NN / 4; i += 1024) {
            float4 v = sc4[i];
            unsigned keys[4] = { __float_as_uint(v.x), __float_as_uint(v.y),
                                 __float_as_uint(v.z), __float_as_uint(v.w) };
#pragma unroll
            for (int j = 0; j < 4; ++j) {
                if (bin_of(keys[j]) >= t) {
                    int pos = atomicAdd(&s_cnt, 1);   // LDS atomic
                    if (pos < CAP)
                        cb[pos] = ((unsigned long long)keys[j] << 32) |
                                  (unsigned)(4 * i + j);
                }
            }
        }
        __syncthreads();
        M = s_cnt; if (M > CAP) M = CAP;
        for (int i = tid; i < NBIN; i += 1024) h[i] = 0u;
        if (tid == 0) s_cnt = 0;
        __syncthreads();
    }

    // ---- candidate hist (stream from global, L2-hot) ----
    for (int j = tid; j < M; j += 1024)
        atomicAdd(&h[bin_of((unsigned)(cb[j] >> 32))], 1u);
    __syncthreads();
    int t2 = rank_bin(h, wtot, &s_t, tid);

    // ---- survivors (bin >= t2) -> LDS; ~210 expected ----
    for (int j = tid; j < M; j += 1024) {
        unsigned long long p = cb[j];
        if (bin_of((unsigned)(p >> 32)) >= t2) {
            int q = atomicAdd(&s_cnt, 1);
            if (q < SVCAP) sv[q] = p;
        }
    }
    __syncthreads();
    int M2 = s_cnt; if (M2 > SVCAP) M2 = SVCAP;
    if (tid == 0) { sv[M2] = 0ull; sv[M2 + 1] = 0ull; }   // pad for b128 reads
    __syncthreads();

    // ---- exact rank by (key desc, idx desc): packed u64, b128 reads ----
    {
        int Mh = (M2 + 1) >> 1;
        const ulonglong2* v2 = (const ulonglong2*)sv;
        for (int j = tid; j < M2; j += 1024) {
            unsigned long long pj = sv[j];
            int rank = 0;
#pragma unroll 4
            for (int mm = 0; mm < Mh; ++mm) {
                ulonglong2 v = v2[mm];
                rank += (v.x > pj) + (v.y > pj);      // 0-pad never counts
            }
            if (rank < TOPK) sel[rank] = pj;
        }
    }
    __syncthreads();

    // ---- NMS-order re-rank: (key<<32)|~idx == (key desc, idx asc) ----
    if (tid < TOPK) {
        unsigned long long p = sel[tid];
        pk2[tid] = (p & 0xffffffff00000000ull) | (unsigned)(~(unsigned)p);
    }
    __syncthreads();
    if (tid < TOPK) {
        unsigned long long pj = pk2[tid];
        int r2 = 0;
        const ulonglong2* p2 = (const ulonglong2*)pk2;
#pragma unroll 4
        for (int mm = 0; mm < TOPK / 2; ++mm) {
            ulonglong2 v = p2[mm];
            r2 += (v.x > pj) + (v.y > pj);
        }
        int idx = (int)(~(unsigned)pj);
        nms_i[r2] = idx;
        nms_xy[r2] = make_float2(sg[2 * (size_t)idx], sg[2 * (size_t)idx + 1]);
    }
    __syncthreads();

    // ---- kill matrix (parallel ballots, proven) ----
    {
        int lane = tid & 63, wv = tid >> 6;
        for (int p = wv; p < TOPK; p += 16) {
            float2 w = nms_xy[p];
#pragma unroll
            for (int k = 0; k < 4; ++k) {
                int j = k * 64 + lane;
                float2 bj = nms_xy[j];
                bool kill = false;
                if (j < TOPK) {
                    if (j == p) kill = true;
                    else {
                        float inter = fminf(bj.y, w.y) - fmaxf(bj.x, w.x);
                        kill = inter > 0.f;
                    }
                }
                unsigned long long bm = __ballot(kill);
                if (lane == 0) krow[p][k] = bm;
            }
        }
    }
    __syncthreads();

    // ---- trivial mask: triv bit p set iff krow[p] == {self} (suppresses
    // nobody else). Built by wave ballots over threads 0..255. ----
    if (tid < 256) {
        int p = tid;
        bool tv = false;
        if (p < TOPK) {
            unsigned long long self0 = (p < 64)  ? (1ull << p) : 0ull;
            unsigned long long self1 = (p >= 64 && p < 128)  ? (1ull << (p - 64)) : 0ull;
            unsigned long long self2 = (p >= 128 && p < 192) ? (1ull << (p - 128)) : 0ull;
            unsigned long long self3 = (p >= 192) ? (1ull << (p - 192)) : 0ull;
            tv = (krow[p][0] == self0) && (krow[p][1] == self1) &&
                 (krow[p][2] == self2) && (krow[p][3] == self3);
        }
        unsigned long long bm = __ballot(tv);
        if ((tid & 63) == 0) trivm[tid >> 6] = bm;
    }
    __syncthreads();

    // ---- thread-0 greedy scan with trivial fast path ----
    if (tid == 0) {
        unsigned long long t0 = trivm[0], t1 = trivm[1], t2m = trivm[2], t3 = trivm[3];
        unsigned long long m0 = ~0ull, m1 = ~0ull, m2 = ~0ull, m3 = 0xffull;
        int* keep = out + b * TOPK;
        for (int it = 0; it < TOPK; ++it) {
            int p;
            if (m0)      p = __ffsll(m0) - 1;
            else if (m1) p = 64 + __ffsll(m1) - 1;
            else if (m2) p = 128 + __ffsll(m2) - 1;
            else if (m3) p = 192 + __ffsll(m3) - 1;
            else break;
            keep[it] = nms_i[p];
            int s2 = p >> 6;
            unsigned long long bit = 1ull << (p & 63);
            bool tvw = (s2 == 0) ? (t0 & bit) : (s2 == 1) ? (t1 & bit)
                     : (s2 == 2) ? (t2m & bit) : (t3 & bit);
            if (tvw) {
                // trivial winner: only clears its own bit (register op)
                if (s2 == 0) m0 &= ~bit;
                else if (s2 == 1) m1 &= ~bit;
                else if (s2 == 2) m2 &= ~bit;
                else m3 &= ~bit;
            } else {
                m0 &= ~krow[p][0];
                m1 &= ~krow[p][1];
                m2 &= ~krow[p][2];
                m3 &= ~krow[p][3];
            }
        }
    }
}

extern "C" void kernel_launch(void* const* d_in, const int* in_sizes, int n_in,
                              void* d_out, int out_size, void* d_ws, size_t ws_size,
                              hipStream_t stream) {
    const float* logits = (const float*)d_in[0];   // (8, 200000, 81) f32
    const float* segs   = (const float*)d_in[1];   // (8, 200000, 2)  f32
    int* out = (int*)d_out;                        // (16, 200) int32

    char* ws = (char*)d_ws;
    float*              scores = (float*)ws;                            // 6,400,000 B
    unsigned long long* cand   = (unsigned long long*)(ws + 6400000);   // 8*16384*8 = 1,048,576 B
    int*                cnt    = (int*)(ws + 6400000 + 1048576);        // 8 lines (1 KB)

    dim3 sgrid(NN / 64, BB);                       // 3125 x 8
    scores_kernel<<<sgrid, 256, 0, stream>>>(logits, scores, cand, cnt);
    final_kernel<<<BB, 1024, 0, stream>>>(scores, segs, cand, cnt, out);
}

// Round 29
// 138.497 us; speedup vs baseline: 1.2347x; 1.0807x over previous
//
#include <hip/hip_runtime.h>
#include <hip/hip_bf16.h>
#include <math.h>

#define BB 8
#define NN 200000
#define CC 81
#define TOPK 200
#define CAP 16384             // per-batch candidate capacity (true c ~5-8K)
#define SVCAP 2048            // survivor capacity (typ. ~210)
#define NBIN 4096
#define THKEY 0x3E800000u     // bits of 0.25f (prefilter threshold)
#define MAGIC 0x5A17C0DEu     // protocol tag: cnt line initialized by final

static __device__ __forceinline__ int bin_of(unsigned key) {
    return (int)((key >> 14) & (NBIN - 1));
}

// ---------------------------------------------------------------------------
// Kernel A (proven, passed R26/R27/R28): scores pipeline + two-phase append.
// 89.6us @ ~92% of achievable HBM BW (measured R11).
// ---------------------------------------------------------------------------
__global__ __launch_bounds__(256) void scores_kernel(const float* __restrict__ logits,
                                                     float* __restrict__ scores,
                                                     unsigned long long* __restrict__ cand,
                                                     int* __restrict__ cnt) {
    __shared__ float ls[64 * CC];     // 5184 floats = 20.7 KB
    __shared__ float lsc[64];
    __shared__ unsigned long long lbuf[64];
    __shared__ int s_app, s_base;
    int tid = threadIdx.x;
    int b = blockIdx.y;
    if (tid == 0) s_app = 0;
    size_t fbase = ((size_t)b * NN + (size_t)blockIdx.x * 64) * CC;  // 16B-aligned
    const float4* g4 = (const float4*)(logits + fbase);
    float4* l4 = (float4*)ls;

    int wbase = tid & ~63;            // wave-uniform base within block
#pragma unroll
    for (int k = 0; k < 5; ++k) {     // 5 full wave rounds = 1280 float4s
        __builtin_amdgcn_global_load_lds(
            (const __attribute__((address_space(1))) void*)(g4 + k * 256 + tid),
            (__attribute__((address_space(3))) void*)(l4 + k * 256 + wbase),
            16, 0, 0);
    }
    if (tid < 16) l4[1280 + tid] = g4[1280 + tid];   // tail 16 f4s, plain copy
    __syncthreads();                  // drains vmcnt incl. global_load_lds

    int r = tid >> 2;                 // row 0..63
    int q = tid & 3;                  // quarter
    const float* row = ls + r * CC;
    int head = (4 - (r & 3)) & 3;     // floats until 16B alignment (81r%4==r%4)
    int nf4 = (CC - head) >> 2;       // 19 or 20 aligned float4s
    int tail = CC - head - 4 * nf4;   // 0..3

    float m = -INFINITY, S = 0.0f;
    const float4* rp = (const float4*)(row + head);
    for (int j = q; j < nf4; j += 4) {
        float4 v = rp[j];
        m = fmaxf(fmaxf(fmaxf(m, v.x), v.y), fmaxf(v.z, v.w));
        S += __expf(v.x) + __expf(v.y) + __expf(v.z) + __expf(v.w);
    }
    if (q == 3) {
        for (int h2 = 0; h2 < head; ++h2) { float x = row[h2]; m = fmaxf(m, x); S += __expf(x); }
        for (int t2 = 0; t2 < tail; ++t2) { float x = row[CC - tail + t2]; m = fmaxf(m, x); S += __expf(x); }
    }
#pragma unroll
    for (int w = 1; w < 4; w <<= 1) {
        m = fmaxf(m, __shfl_xor(m, w, 64));
        S += __shfl_xor(S, w, 64);
    }
    if (q == 0) {
        float s = __expf(m) / S;
        lsc[r] = s;
        unsigned key = __float_as_uint(s);
        if (key >= THKEY) {
            int p = atomicAdd(&s_app, 1);        // LDS atomic, <=64 per block
            lbuf[p] = ((unsigned long long)key << 32) |
                      (unsigned)(blockIdx.x * 64 + r);
        }
    }
    __syncthreads();
    if (tid < 64) scores[(size_t)b * NN + (size_t)blockIdx.x * 64 + tid] = lsc[tid];
    int na = s_app;
    if (na > 0) {
        if (tid == 0) s_base = atomicAdd(&cnt[b * 32], na);   // ONE global RMW
        __syncthreads();
        if (tid < na) {
            int pos = s_base + tid;
            if (pos >= 0 && pos < CAP) cand[(size_t)b * CAP + pos] = lbuf[tid];
        }
    }
}

// ---------------------------------------------------------------------------
// rank_bin (proven R22-R28).
// ---------------------------------------------------------------------------
static __device__ __forceinline__ int rank_bin(unsigned* h, unsigned* wtot,
                                               int* s_t, int tid) {
    int lane = tid & 63, wv = tid >> 6;
    unsigned s = 0;
    int hi = NBIN - 1 - 16 * tid;
    if (tid < 256) {
#pragma unroll
        for (int j = 0; j < 16; ++j) s += h[hi - j];
    }
    unsigned inc = s;
#pragma unroll
    for (int d = 1; d < 64; d <<= 1) {
        unsigned o = __shfl_up(inc, d, 64);
        if (lane >= d) inc += o;
    }
    if (tid < 256 && lane == 63) wtot[wv] = inc;
    __syncthreads();
    if (tid < 256) {
        unsigned before = inc - s;
        for (int wp = 0; wp < wv; ++wp) before += wtot[wp];
        if (before < TOPK && before + s >= TOPK) {
            unsigned cum = before;
            for (int j = 0; j < 16; ++j) {
                cum += h[hi - j];
                if (cum >= TOPK) { *s_t = hi - j; break; }
            }
        }
    }
    __syncthreads();
    return *s_t;
}

// ---------------------------------------------------------------------------
// Kernel F (v9, proven R26 @ 140.7us — byte-identical revert; R28's
// trivial-mask variant regressed): magic-tag self-zero, global-streamed
// candidates, hist -> rank-200 bin -> survivors -> packed-u64 rank/re-rank
// -> kill matrix (parallel ballots) -> single-thread LDS greedy scan.
// ---------------------------------------------------------------------------
__global__ __launch_bounds__(1024) void final_kernel(const float* __restrict__ scores,
                                                     const float* __restrict__ segs,
                                                     unsigned long long* __restrict__ cand,
                                                     int* __restrict__ cnt,
                                                     int* __restrict__ out) {
    __shared__ unsigned h[NBIN];                                 // 16 KB
    __shared__ unsigned wtot[4];
    __shared__ int s_t, s_cnt;
    __shared__ __align__(16) unsigned long long sv[SVCAP + 2];   // 16.4 KB
    __shared__ __align__(16) unsigned long long sel[TOPK];
    __shared__ __align__(16) unsigned long long pk2[TOPK];
    __shared__ int nms_i[256];
    __shared__ float2 nms_xy[256];
    __shared__ __align__(32) unsigned long long krow[TOPK][4];   // 6.4 KB

    int b = blockIdx.x;
    int tid = threadIdx.x;
    const float* sc = scores + (size_t)b * NN;
    const float* sg = segs + (size_t)b * NN * 2;
    unsigned long long* cb = cand + (size_t)b * CAP;

    for (int i = tid; i < TOPK; i += 1024) {
        out[b * TOPK + i] = 0;
        out[(BB + b) * TOPK + i] = 0;
    }
    if (tid < 256) { nms_xy[tid] = make_float2(0.f, 0.f); nms_i[tid] = 0; }
    for (int i = tid; i < NBIN; i += 1024) h[i] = 0u;
    if (tid == 0) s_cnt = 0;

    int c = cnt[b * 32];
    unsigned mg = (unsigned)cnt[b * 32 + 1];
    __syncthreads();                  // all threads have read c/mg
    if (tid == 0) { cnt[b * 32] = 0; cnt[b * 32 + 1] = (int)MAGIC; }  // next replay

    int M;
    if (mg == MAGIC && c >= TOPK && c <= CAP) {
        M = c;                         // FAST: candidates valid in cand
    } else {
        // SLOW: full-scan hist -> threshold -> gather into cand
        const float4* sc4 = (const float4*)sc;
        for (int i = tid; i < NN / 4; i += 1024) {
            float4 v = sc4[i];
            atomicAdd(&h[bin_of(__float_as_uint(v.x))], 1u);
            atomicAdd(&h[bin_of(__float_as_uint(v.y))], 1u);
            atomicAdd(&h[bin_of(__float_as_uint(v.z))], 1u);
            atomicAdd(&h[bin_of(__float_as_uint(v.w))], 1u);
        }
        __syncthreads();
        int t = rank_bin(h, wtot, &s_t, tid);
        for (int i = tid; i < NN / 4; i += 1024) {
            float4 v = sc4[i];
            unsigned keys[4] = { __float_as_uint(v.x), __float_as_uint(v.y),
                                 __float_as_uint(v.z), __float_as_uint(v.w) };
#pragma unroll
            for (int j = 0; j < 4; ++j) {
                if (bin_of(keys[j]) >= t) {
                    int pos = atomicAdd(&s_cnt, 1);   // LDS atomic
                    if (pos < CAP)
                        cb[pos] = ((unsigned long long)keys[j] << 32) |
                                  (unsigned)(4 * i + j);
                }
            }
        }
        __syncthreads();
        M = s_cnt; if (M > CAP) M = CAP;
        for (int i = tid; i < NBIN; i += 1024) h[i] = 0u;
        if (tid == 0) s_cnt = 0;
        __syncthreads();
    }

    // ---- candidate hist (stream from global, L2-hot) ----
    for (int j = tid; j < M; j += 1024)
        atomicAdd(&h[bin_of((unsigned)(cb[j] >> 32))], 1u);
    __syncthreads();
    int t2 = rank_bin(h, wtot, &s_t, tid);

    // ---- survivors (bin >= t2) -> LDS; ~210 expected ----
    for (int j = tid; j < M; j += 1024) {
        unsigned long long p = cb[j];
        if (bin_of((unsigned)(p >> 32)) >= t2) {
            int q = atomicAdd(&s_cnt, 1);
            if (q < SVCAP) sv[q] = p;
        }
    }
    __syncthreads();
    int M2 = s_cnt; if (M2 > SVCAP) M2 = SVCAP;
    if (tid == 0) { sv[M2] = 0ull; sv[M2 + 1] = 0ull; }   // pad for b128 reads
    __syncthreads();

    // ---- exact rank by (key desc, idx desc): packed u64, b128 reads ----
    {
        int Mh = (M2 + 1) >> 1;
        const ulonglong2* v2 = (const ulonglong2*)sv;
        for (int j = tid; j < M2; j += 1024) {
            unsigned long long pj = sv[j];
            int rank = 0;
#pragma unroll 4
            for (int mm = 0; mm < Mh; ++mm) {
                ulonglong2 v = v2[mm];
                rank += (v.x > pj) + (v.y > pj);      // 0-pad never counts
            }
            if (rank < TOPK) sel[rank] = pj;
        }
    }
    __syncthreads();

    // ---- NMS-order re-rank: (key<<32)|~idx == (key desc, idx asc) ----
    if (tid < TOPK) {
        unsigned long long p = sel[tid];
        pk2[tid] = (p & 0xffffffff00000000ull) | (unsigned)(~(unsigned)p);
    }
    __syncthreads();
    if (tid < TOPK) {
        unsigned long long pj = pk2[tid];
        int r2 = 0;
        const ulonglong2* p2 = (const ulonglong2*)pk2;
#pragma unroll 4
        for (int mm = 0; mm < TOPK / 2; ++mm) {
            ulonglong2 v = p2[mm];
            r2 += (v.x > pj) + (v.y > pj);
        }
        int idx = (int)(~(unsigned)pj);
        nms_i[r2] = idx;
        nms_xy[r2] = make_float2(sg[2 * (size_t)idx], sg[2 * (size_t)idx + 1]);
    }
    __syncthreads();

    // ---- kill matrix (parallel ballots) ----
    {
        int lane = tid & 63, wv = tid >> 6;
        for (int p = wv; p < TOPK; p += 16) {
            float2 w = nms_xy[p];
#pragma unroll
            for (int k = 0; k < 4; ++k) {
                int j = k * 64 + lane;
                float2 bj = nms_xy[j];
                bool kill = false;
                if (j < TOPK) {
                    if (j == p) kill = true;
                    else {
                        float inter = fminf(bj.y, w.y) - fmaxf(bj.x, w.x);
                        kill = inter > 0.f;
                    }
                }
                unsigned long long bm = __ballot(kill);
                if (lane == 0) krow[p][k] = bm;
            }
        }
    }
    __syncthreads();

    // ---- single-thread greedy scan: ffs + 4 independent LDS b64 reads ----
    if (tid == 0) {
        unsigned long long m0 = ~0ull, m1 = ~0ull, m2 = ~0ull, m3 = 0xffull;
        int* keep = out + b * TOPK;
        for (int it = 0; it < TOPK; ++it) {
            int p;
            if (m0)      p = __ffsll(m0) - 1;
            else if (m1) p = 64 + __ffsll(m1) - 1;
            else if (m2) p = 128 + __ffsll(m2) - 1;
            else if (m3) p = 192 + __ffsll(m3) - 1;
            else break;
            keep[it] = nms_i[p];
            m0 &= ~krow[p][0];
            m1 &= ~krow[p][1];
            m2 &= ~krow[p][2];
            m3 &= ~krow[p][3];
        }
    }
}

extern "C" void kernel_launch(void* const* d_in, const int* in_sizes, int n_in,
                              void* d_out, int out_size, void* d_ws, size_t ws_size,
                              hipStream_t stream) {
    const float* logits = (const float*)d_in[0];   // (8, 200000, 81) f32
    const float* segs   = (const float*)d_in[1];   // (8, 200000, 2)  f32
    int* out = (int*)d_out;                        // (16, 200) int32

    char* ws = (char*)d_ws;
    float*              scores = (float*)ws;                            // 6,400,000 B
    unsigned long long* cand   = (unsigned long long*)(ws + 6400000);   // 8*16384*8 = 1,048,576 B
    int*                cnt    = (int*)(ws + 6400000 + 1048576);        // 8 lines (1 KB)

    dim3 sgrid(NN / 64, BB);                       // 3125 x 8
    scores_kernel<<<sgrid, 256, 0, stream>>>(logits, scores, cand, cnt);
    final_kernel<<<BB, 1024, 0, stream>>>(scores, segs, cand, cnt, out);
}